// Round 1
// baseline (709.932 us; speedup 1.0000x reference)
//
#include <hip/hip_runtime.h>
#include <math.h>

#define SZ 80
#define SS (SZ*SZ)        // 6400
#define VOX (SZ*SZ*SZ)    // 512000
#define CMID 72
#define COUT 60
#define EPSF 1e-5f

// ---------------------------------------------------------------------------
// softstep(t) = t>0 ? exp(-1/t) : 0   (fp32, matches JAX)
__device__ __forceinline__ float softstep(float t){
    return t > 0.0f ? expf(-1.0f/t) : 0.0f;
}

// ---------------------------------------------------------------------------
// Build the 72x4x3x3x3 conv kernel, stored as [k_idx(27)][cin(4)][c(72)].
__global__ void k_build_weights(const float* __restrict__ Wtp, float* __restrict__ wout){
    int idx = blockIdx.x*256 + threadIdx.x;
    if (idx >= 27*4*72) return;
    int c   = idx % 72;
    int cin = (idx/72) & 3;
    int ki  = idx / 288;
    int kz = ki % 3, ky = (ki/3) % 3, kx = ki/9;
    float rx = (float)(kx-1), ry = (float)(ky-1), rz = (float)(kz-1);
    float norm = sqrtf(rx*rx + ry*ry + rz*rz);
    float den = fmaxf(norm, 1e-12f);
    float ux = rx/den, uy = ry/den, uz = rz/den;
    const float C0 = 8.433573069074764f;   // 1.14136 * e^2
    float emb[4];
    #pragma unroll
    for (int r=0;r<4;++r){
        float v = 0.2f*(float)(r+1);
        float d = (norm - v) / 0.2f;
        emb[r] = C0 * softstep(d+1.0f) * softstep(1.0f-d);
    }
    int p; float factor;
    if (c < 28) { p = cin*28 + c; factor = 1.0f; }
    else if (c < 52) {
        int m = (c-28)/3, j = (c-28)%3;
        p = 112 + cin*8 + m;
        float u3[3]; u3[0]=ux; u3[1]=uy; u3[2]=uz;
        factor = 1.7320508075688772f * u3[j];        // sqrt(3)*u
    } else {
        int m = (c-52)/5, j = (c-52)%5;
        p = 144 + cin*4 + m;
        const float s15 = 3.872983346207417f, s5 = 2.23606797749979f;
        float y2;
        if      (j==0) y2 = s15*ux*uy;
        else if (j==1) y2 = s15*uy*uz;
        else if (j==2) y2 = 0.5f*s5*(2.0f*uz*uz - ux*ux - uy*uy);
        else if (j==3) y2 = s15*ux*uz;
        else           y2 = 0.5f*s15*(ux*ux - uy*uy);
        factor = y2;
    }
    float w = (emb[0]*Wtp[p] + emb[1]*Wtp[160+p] + emb[2]*Wtp[320+p] + emb[3]*Wtp[480+p])
              * (1.0f/5.196152422706632f);          // / K^1.5
    wout[idx] = w * factor * 0.5f;                  // / sqrt(CIN)
}

// ---------------------------------------------------------------------------
// Shared conv body: tile = 2x8x16 output voxels per 256-thread block.
// Grid: 4000 blocks = b(2) * xt(40) * yt(10) * zt(5).
__device__ __forceinline__ void conv_tile(const float* __restrict__ xin,
                                          const float* __restrict__ wg,
                                          int bid, float* xs, float* wl,
                                          float acc[CMID], int& b, int& vox)
{
    int tid = threadIdx.x;
    int zt = bid % 5, yt = (bid/5) % 10, xt = (bid/50) % 40;
    b = bid / 2000;
    int X0 = xt*2, Y0 = yt*8, Z0 = zt*16;

    for (int l = tid; l < 7776; l += 256) wl[l] = wg[l];

    // halo tile: [ci(4)][x(4)][y(10)][z(18)]
    for (int l = tid; l < 2880; l += 256){
        int zz = l % 18;
        int yy = (l/18) % 10;
        int xx = (l/180) % 4;
        int ci = l/720;
        int gx = X0-1+xx, gy = Y0-1+yy, gz = Z0-1+zz;
        float v = 0.0f;
        if ((unsigned)gx < 80u && (unsigned)gy < 80u && (unsigned)gz < 80u)
            v = xin[(size_t)(b*4+ci)*VOX + gx*SS + gy*SZ + gz];
        xs[l] = v;
    }
    __syncthreads();

    int lz = tid & 15, ly = (tid>>4) & 7, lx = tid>>7;
    #pragma unroll
    for (int c=0;c<CMID;++c) acc[c]=0.0f;

    for (int ci=0; ci<4; ++ci)
      for (int kx=0;kx<3;++kx)
        for (int ky=0;ky<3;++ky)
          #pragma unroll
          for (int kz=0;kz<3;++kz){
            float xv = xs[((ci*4 + lx+kx)*10 + ly+ky)*18 + lz+kz];
            const float* wp = &wl[(((kx*3+ky)*3+kz)*4+ci)*72];
            #pragma unroll
            for (int c=0;c<72;++c) acc[c] = fmaf(xv, wp[c], acc[c]);
          }
    int gx = X0+lx, gy = Y0+ly, gz = Z0+lz;
    vox = gx*SS + gy*SZ + gz;
}

// ---------------------------------------------------------------------------
// Pass 1: conv + per-block stat partials (68 per block):
//   [0..27] sum(s) ; [28..55] sum(s^2) ; [56..63] sum(v1^2 grp) ; [64..67] sum(v2^2 grp)
__global__ __launch_bounds__(256) void k_conv_stats(const float* __restrict__ xin,
        const float* __restrict__ wg, float* __restrict__ partials)
{
    __shared__ float xs[2880];
    __shared__ float wl[7776];
    __shared__ float red[4][68];
    float acc[CMID];
    int b, vox;
    conv_tile(xin, wg, blockIdx.x, xs, wl, acc, b, vox);
    (void)vox; (void)b;

    int tid = threadIdx.x, lane = tid & 63, wid = tid >> 6;
    #pragma unroll
    for (int s=0;s<68;++s){
        float v;
        if (s < 28)      v = acc[s];
        else if (s < 56) { float a = acc[s-28]; v = a*a; }
        else if (s < 64) {
            int m = s-56;
            v = acc[28+3*m]*acc[28+3*m] + acc[29+3*m]*acc[29+3*m] + acc[30+3*m]*acc[30+3*m];
        } else {
            int m = s-64;
            v = acc[52+5*m+0]*acc[52+5*m+0] + acc[52+5*m+1]*acc[52+5*m+1]
              + acc[52+5*m+2]*acc[52+5*m+2] + acc[52+5*m+3]*acc[52+5*m+3]
              + acc[52+5*m+4]*acc[52+5*m+4];
        }
        v += __shfl_down(v, 32);
        v += __shfl_down(v, 16);
        v += __shfl_down(v, 8);
        v += __shfl_down(v, 4);
        v += __shfl_down(v, 2);
        v += __shfl_down(v, 1);
        if (lane == 0) red[wid][s] = v;
    }
    __syncthreads();
    if (tid < 68)
        partials[(size_t)blockIdx.x*68 + tid] = red[0][tid]+red[1][tid]+red[2][tid]+red[3][tid];
}

// ---------------------------------------------------------------------------
// Pass 2: reduce 2000 tile-partials per (b,stat) -> stats[b*68+s]
__global__ __launch_bounds__(256) void k_reduce_stats(const float* __restrict__ partials,
                                                      float* __restrict__ stats)
{
    int j = blockIdx.x;            // 0..135
    int b = j / 68, s = j % 68;
    float acc = 0.0f;
    for (int t = threadIdx.x; t < 2000; t += 256)
        acc += partials[((size_t)(b*2000+t))*68 + s];
    acc += __shfl_down(acc, 32);
    acc += __shfl_down(acc, 16);
    acc += __shfl_down(acc, 8);
    acc += __shfl_down(acc, 4);
    acc += __shfl_down(acc, 2);
    acc += __shfl_down(acc, 1);
    __shared__ float red[4];
    if ((threadIdx.x & 63)==0) red[threadIdx.x>>6] = acc;
    __syncthreads();
    if (threadIdx.x==0) stats[j] = red[0]+red[1]+red[2]+red[3];
}

// ---------------------------------------------------------------------------
// Pass 3: conv again + instance-norm + gate + write 60 output channels
__global__ __launch_bounds__(256) void k_conv_finish(const float* __restrict__ xin,
        const float* __restrict__ wg, const float* __restrict__ stats,
        const float* __restrict__ bnw, const float* __restrict__ bnb,
        float* __restrict__ out)
{
    __shared__ float xs[2880];
    __shared__ float wl[7776];
    float acc[CMID];
    int b, vox;
    conv_tile(xin, wg, blockIdx.x, xs, wl, acc, b, vox);

    const float* st = stats + b*68;
    float* op = out + (size_t)b*COUT*VOX + vox;
    const float invN = 1.0f/512000.0f;

    // gates from normalized channels 16..27
    float g[12];
    #pragma unroll
    for (int m=0;m<12;++m){
        int c = 16+m;
        float mean = st[c]*invN;
        float var  = st[28+c]*invN - mean*mean;
        float sn   = (acc[c]-mean) * (1.0f/sqrtf(var+EPSF)) * bnw[c] + bnb[c];
        g[m] = 1.8464f / (1.0f + expf(-sn));
    }
    // scalar channels 0..15 -> out 0..15
    #pragma unroll
    for (int c=0;c<16;++c){
        float mean = st[c]*invN;
        float var  = st[28+c]*invN - mean*mean;
        float sn   = (acc[c]-mean) * (1.0f/sqrtf(var+EPSF)) * bnw[c] + bnb[c];
        op[(size_t)c*VOX] = 1.4142135623730951f * fmaxf(sn, 0.0f);
    }
    // v1: h ch 28..51 -> out 16..39
    #pragma unroll
    for (int m=0;m<8;++m){
        float n1 = st[56+m] * (1.0f/(3.0f*512000.0f));
        float sc = (1.0f/sqrtf(n1+EPSF)) * bnw[28+m] * g[m];
        #pragma unroll
        for (int jj=0;jj<3;++jj)
            op[(size_t)(16+3*m+jj)*VOX] = acc[28+3*m+jj]*sc;
    }
    // v2: h ch 52..71 -> out 40..59
    #pragma unroll
    for (int m=0;m<4;++m){
        float n2 = st[64+m] * (1.0f/(5.0f*512000.0f));
        float sc = (1.0f/sqrtf(n2+EPSF)) * bnw[36+m] * g[8+m];
        #pragma unroll
        for (int jj=0;jj<5;++jj)
            op[(size_t)(40+5*m+jj)*VOX] = acc[52+5*m+jj]*sc;
    }
}

// ---------------------------------------------------------------------------
extern "C" void kernel_launch(void* const* d_in, const int* in_sizes, int n_in,
                              void* d_out, int out_size, void* d_ws, size_t ws_size,
                              hipStream_t stream)
{
    const float* x   = (const float*)d_in[0];
    const float* Wtp = (const float*)d_in[1];
    const float* bnw = (const float*)d_in[2];
    const float* bnb = (const float*)d_in[3];
    float* ws       = (float*)d_ws;
    float* wgt      = ws;                    // 7776 floats
    float* partials = ws + 8192;             // 4000*68 = 272000 floats
    float* stats    = ws + 8192 + 272000;    // 136 floats

    k_build_weights<<<31, 256, 0, stream>>>(Wtp, wgt);
    k_conv_stats  <<<4000, 256, 0, stream>>>(x, wgt, partials);
    k_reduce_stats<<<136, 256, 0, stream>>>(partials, stats);
    k_conv_finish <<<4000, 256, 0, stream>>>(x, wgt, stats, bnw, bnb, (float*)d_out);
}